// Round 14
// baseline (287.009 us; speedup 1.0000x reference)
//
#include <hip/hip_runtime.h>
#include <cstdint>
#include <cstddef>

#define DD 64

typedef float    f32x4  __attribute__((ext_vector_type(4)));
typedef _Float16 f16x8  __attribute__((ext_vector_type(8)));
typedef _Float16 f16x4  __attribute__((ext_vector_type(4)));

__device__ __forceinline__ float sigmoidf_(float x) {
    return 1.0f / (1.0f + __expf(-x));
}
__device__ __forceinline__ float tanh_fast(float x) {
    float ax = fabsf(x);
    float t = 1.0f - 2.0f / (1.0f + __expf(2.0f * ax));
    return copysignf(t, x);
}
__device__ __forceinline__ f32x4 MFMA(f32x4 c, f16x8 a, f16x8 b) {
    return __builtin_amdgcn_mfma_f32_16x16x32_f16(a, b, c, 0, 0, 0);
}

// ---------------- fused: B-fragment build (blocks 0..15) + winner init ----------------
__global__ void k_prep_init(const float* __restrict__ Wih, const float* __restrict__ Whh,
                            _Float16* __restrict__ bhi, _Float16* __restrict__ blo,
                            int* __restrict__ winner, int num_nodes)
{
    if (blockIdx.x < 16) {
        int f = blockIdx.x * 4 + (threadIdx.x >> 6);   // 0..63
        int l = threadIdx.x & 63;
        int g = f >> 2, s = f & 3;
        int c = g * 16 + (l & 15);
        int grp = c >> 6, dd = c & 63;
        int kbase = s * 32 + (l >> 4) * 8;
        int row = (grp == 0) ? dd : (grp == 1) ? 64 + dd : 128 + dd;

        f16x8 hv, lv;
        for (int j = 0; j < 8; ++j) {
            int k = kbase + j;
            float v;
            if (grp <= 1)      v = (k < 64) ? Wih[row * 64 + k] : Whh[row * 64 + (k - 64)];
            else if (grp == 2) v = (k < 64) ? Wih[row * 64 + k] : 0.0f;
            else               v = (k < 64) ? 0.0f : Whh[row * 64 + (k - 64)];
            _Float16 h = (_Float16)v;
            hv[j] = h;
            lv[j] = (_Float16)(v - (float)h);
        }
        size_t off = ((size_t)f * 64 + l);
        ((f16x8*)bhi)[off] = hv;
        ((f16x8*)blo)[off] = lv;
    } else {
        int i = (int)(blockIdx.x - 16) * 256 + threadIdx.x;
        if (i < num_nodes) winner[i] = -1;
    }
}

// ---------------- vote + dt precompute ----------------
__global__ void k_vote_dt(const int* __restrict__ ids, const float* __restrict__ ts,
                          const float* __restrict__ lut, int* __restrict__ winner,
                          float* __restrict__ dtw, int n) {
    int i = blockIdx.x * blockDim.x + threadIdx.x;
    if (i < n) {
        int id = ids[i];
        atomicMax(&winner[id], i);
        dtw[i] = ts[i] - lut[id];
    }
}

// ---------------- main GRU kernel: 128 events/block, 2-chunk software pipeline ----------------
// Chunk1's 8 gather loads (32 VGPR held) are issued BEFORE chunk0's MFMA and land
// under it; only chunk0's staging window is latency-exposed. Budget: B-frags 72 +
// held 32 + working ~40 ~= 145 regs <= ~170 cap at launch_bounds(256,3).
__global__ __launch_bounds__(256, 3) void k_gru(
    const int* __restrict__ ids,
    const float* __restrict__ emb,
    const float* __restrict__ mem,
    const float* __restrict__ Wt,
    const float* __restrict__ bt,
    const float* __restrict__ bih,
    const float* __restrict__ bhh,
    const _Float16* __restrict__ bhi,
    const _Float16* __restrict__ blo,
    const int* __restrict__ winner,
    const float* __restrict__ dtw,
    float* __restrict__ out0,
    float* __restrict__ out1,
    int n)
{
    __shared__ _Float16 xhh[64][136];   // hi plane: [event][k], k<64 x_hi, k>=64 h
    __shared__ _Float16 xhl[64][72];    // lo plane: x_lo only (k<64)
    __shared__ int sid[128];
    __shared__ int swin[128];

    const int w    = threadIdx.x >> 6;
    const int l    = threadIdx.x & 63;
    const int col  = l & 15;
    const int rowg = l >> 4;
    const int d    = w * 16 + col;

    const long base = (long)blockIdx.x * 128;
    const bool full = (base + 128 <= (long)n);

    // ---- phase A: coalesced scalars for BOTH chunks ----
    const int  e16 = w * 16 + col;
    const long evA = base + e16;
    const long evB = evA + 64;
    int idA = 0, winA = 0, idB = 0, winB = 0;
    float dtA = 0.f, dtB = 0.f;
    if (full || evA < n) {
        idA  = ids[evA];
        dtA  = dtw[evA];
        winA = (winner[idA] == (int)evA) ? 1 : 0;
    }
    if (full || evB < n) {
        idB  = ids[evB];
        dtB  = dtw[evB];
        winB = (winner[idB] == (int)evB) ? 1 : 0;
    }
    if (l < 16) {
        sid[e16]      = idA;  swin[e16]      = winA;
        sid[64 + e16] = idB;  swin[64 + e16] = winB;
    }

    int ia0 = __shfl(idA, 0 + rowg),  ia1 = __shfl(idA, 4 + rowg);
    int ia2 = __shfl(idA, 8 + rowg),  ia3 = __shfl(idA, 12 + rowg);
    int ib0 = __shfl(idB, 0 + rowg),  ib1 = __shfl(idB, 4 + rowg);
    int ib2 = __shfl(idB, 8 + rowg),  ib3 = __shfl(idB, 12 + rowg);
    float da0 = __shfl(dtA, 0 + rowg), da1 = __shfl(dtA, 4 + rowg);
    float da2 = __shfl(dtA, 8 + rowg), da3 = __shfl(dtA, 12 + rowg);
    float db0 = __shfl(dtB, 0 + rowg), db1 = __shfl(dtB, 4 + rowg);
    float db2 = __shfl(dtB, 8 + rowg), db3 = __shfl(dtB, 12 + rowg);

    const f32x4* emb4 = (const f32x4*)emb;
    const f32x4* mem4 = (const f32x4*)mem;
    const f32x4 wt4 = ((const f32x4*)Wt)[col];
    const f32x4 bt4 = ((const f32x4*)bt)[col];

    #define CONV_WRITE(XV, HV, DT, IT)                                           \
    {                                                                            \
        int r = w * 16 + (IT) * 4 + rowg;                                        \
        f32x4 x = XV;                                                            \
        x.x = fmaf(DT, wt4.x, x.x + bt4.x);                                      \
        x.y = fmaf(DT, wt4.y, x.y + bt4.y);                                      \
        x.z = fmaf(DT, wt4.z, x.z + bt4.z);                                      \
        x.w = fmaf(DT, wt4.w, x.w + bt4.w);                                      \
        f16x4 xh, xl, hh;                                                        \
        _Float16 a;                                                              \
        a = (_Float16)x.x; xh[0] = a; xl[0] = (_Float16)(x.x - (float)a);        \
        a = (_Float16)x.y; xh[1] = a; xl[1] = (_Float16)(x.y - (float)a);        \
        a = (_Float16)x.z; xh[2] = a; xl[2] = (_Float16)(x.z - (float)a);        \
        a = (_Float16)x.w; xh[3] = a; xl[3] = (_Float16)(x.w - (float)a);        \
        hh[0] = (_Float16)(HV).x; hh[1] = (_Float16)(HV).y;                      \
        hh[2] = (_Float16)(HV).z; hh[3] = (_Float16)(HV).w;                      \
        *(f16x4*)&xhh[r][col * 4]      = xh;                                     \
        *(f16x4*)&xhl[r][col * 4]      = xl;                                     \
        *(f16x4*)&xhh[r][64 + col * 4] = hh;                                     \
    }

    // ---- chunk0: load ----
    f32x4 x0, x1, x2, x3, h0, h1, h2, h3;
    if (full) {
        x0 = __builtin_nontemporal_load(&emb4[(size_t)(base + w * 16 + 0  + rowg) * 16 + col]);
        x1 = __builtin_nontemporal_load(&emb4[(size_t)(base + w * 16 + 4  + rowg) * 16 + col]);
        x2 = __builtin_nontemporal_load(&emb4[(size_t)(base + w * 16 + 8  + rowg) * 16 + col]);
        x3 = __builtin_nontemporal_load(&emb4[(size_t)(base + w * 16 + 12 + rowg) * 16 + col]);
        h0 = mem4[(size_t)ia0 * 16 + col];
        h1 = mem4[(size_t)ia1 * 16 + col];
        h2 = mem4[(size_t)ia2 * 16 + col];
        h3 = mem4[(size_t)ia3 * 16 + col];
    } else {
        f32x4 z = {0.f, 0.f, 0.f, 0.f};
        x0 = x1 = x2 = x3 = h0 = h1 = h2 = h3 = z;
        if (base + w * 16 + 0  + rowg < n) { x0 = emb4[(size_t)(base + w * 16 + 0  + rowg) * 16 + col]; h0 = mem4[(size_t)ia0 * 16 + col]; }
        if (base + w * 16 + 4  + rowg < n) { x1 = emb4[(size_t)(base + w * 16 + 4  + rowg) * 16 + col]; h1 = mem4[(size_t)ia1 * 16 + col]; }
        if (base + w * 16 + 8  + rowg < n) { x2 = emb4[(size_t)(base + w * 16 + 8  + rowg) * 16 + col]; h2 = mem4[(size_t)ia2 * 16 + col]; }
        if (base + w * 16 + 12 + rowg < n) { x3 = emb4[(size_t)(base + w * 16 + 12 + rowg) * 16 + col]; h3 = mem4[(size_t)ia3 * 16 + col]; }
    }

    // ---- chunk0: convert into LDS ----
    CONV_WRITE(x0, h0, da0, 0)
    CONV_WRITE(x1, h1, da1, 1)
    CONV_WRITE(x2, h2, da2, 2)
    CONV_WRITE(x3, h3, da3, 3)

    // ---- chunk1: issue loads NOW (land under chunk0's MFMA); regs reused x0..h3 ----
    if (full) {
        x0 = __builtin_nontemporal_load(&emb4[(size_t)(base + 64 + w * 16 + 0  + rowg) * 16 + col]);
        x1 = __builtin_nontemporal_load(&emb4[(size_t)(base + 64 + w * 16 + 4  + rowg) * 16 + col]);
        x2 = __builtin_nontemporal_load(&emb4[(size_t)(base + 64 + w * 16 + 8  + rowg) * 16 + col]);
        x3 = __builtin_nontemporal_load(&emb4[(size_t)(base + 64 + w * 16 + 12 + rowg) * 16 + col]);
        h0 = mem4[(size_t)ib0 * 16 + col];
        h1 = mem4[(size_t)ib1 * 16 + col];
        h2 = mem4[(size_t)ib2 * 16 + col];
        h3 = mem4[(size_t)ib3 * 16 + col];
    } else {
        f32x4 z = {0.f, 0.f, 0.f, 0.f};
        x0 = x1 = x2 = x3 = h0 = h1 = h2 = h3 = z;
        if (base + 64 + w * 16 + 0  + rowg < n) { x0 = emb4[(size_t)(base + 64 + w * 16 + 0  + rowg) * 16 + col]; h0 = mem4[(size_t)ib0 * 16 + col]; }
        if (base + 64 + w * 16 + 4  + rowg < n) { x1 = emb4[(size_t)(base + 64 + w * 16 + 4  + rowg) * 16 + col]; h1 = mem4[(size_t)ib1 * 16 + col]; }
        if (base + 64 + w * 16 + 8  + rowg < n) { x2 = emb4[(size_t)(base + 64 + w * 16 + 8  + rowg) * 16 + col]; h2 = mem4[(size_t)ib2 * 16 + col]; }
        if (base + 64 + w * 16 + 12 + rowg < n) { x3 = emb4[(size_t)(base + 64 + w * 16 + 12 + rowg) * 16 + col]; h3 = mem4[(size_t)ib3 * 16 + col]; }
    }

    // ---- B fragments (L2-resident), issued alongside chunk1's gathers ----
    const f16x8* H = (const f16x8*)bhi;
    const f16x8* L = (const f16x8*)blo;
    f16x8 BRh0 = H[(size_t)(w * 4 + 0) * 64 + l];
    f16x8 BRh1 = H[(size_t)(w * 4 + 1) * 64 + l];
    f16x8 BRh2 = H[(size_t)(w * 4 + 2) * 64 + l];
    f16x8 BRh3 = H[(size_t)(w * 4 + 3) * 64 + l];
    f16x8 BRl0 = L[(size_t)(w * 4 + 0) * 64 + l];
    f16x8 BRl1 = L[(size_t)(w * 4 + 1) * 64 + l];
    f16x8 BZh0 = H[(size_t)((4 + w) * 4 + 0) * 64 + l];
    f16x8 BZh1 = H[(size_t)((4 + w) * 4 + 1) * 64 + l];
    f16x8 BZh2 = H[(size_t)((4 + w) * 4 + 2) * 64 + l];
    f16x8 BZh3 = H[(size_t)((4 + w) * 4 + 3) * 64 + l];
    f16x8 BZl0 = L[(size_t)((4 + w) * 4 + 0) * 64 + l];
    f16x8 BZl1 = L[(size_t)((4 + w) * 4 + 1) * 64 + l];
    f16x8 BIh0 = H[(size_t)((8 + w) * 4 + 0) * 64 + l];
    f16x8 BIh1 = H[(size_t)((8 + w) * 4 + 1) * 64 + l];
    f16x8 BIl0 = L[(size_t)((8 + w) * 4 + 0) * 64 + l];
    f16x8 BIl1 = L[(size_t)((8 + w) * 4 + 1) * 64 + l];
    f16x8 BHh0 = H[(size_t)((12 + w) * 4 + 2) * 64 + l];
    f16x8 BHh1 = H[(size_t)((12 + w) * 4 + 3) * 64 + l];
    __builtin_amdgcn_sched_barrier(0);   // pin: chunk1 loads + B-frags issued pre-barrier

    const float bR  = bih[d] + bhh[d];
    const float bZ  = bih[64 + d] + bhh[64 + d];
    const float bIN = bih[128 + d];
    const float bHN = bhh[128 + d];

    __syncthreads();

    #define DO_MFMA_EPI(CB)                                                      \
    {                                                                            \
        _Pragma("unroll")                                                        \
        for (int mt = 0; mt < 4; ++mt) {                                         \
            const int arow = mt * 16 + col;                                      \
            const int k0   = rowg * 8;                                           \
            f16x8 Ah0 = *(const f16x8*)&xhh[arow][0 * 32 + k0];                  \
            f16x8 Ah1 = *(const f16x8*)&xhh[arow][1 * 32 + k0];                  \
            f16x8 Ah2 = *(const f16x8*)&xhh[arow][2 * 32 + k0];                  \
            f16x8 Ah3 = *(const f16x8*)&xhh[arow][3 * 32 + k0];                  \
            f16x8 Al0 = *(const f16x8*)&xhl[arow][0 * 32 + k0];                  \
            f16x8 Al1 = *(const f16x8*)&xhl[arow][1 * 32 + k0];                  \
            f32x4 aR = {0,0,0,0}, aZ = {0,0,0,0}, aI = {0,0,0,0}, aH = {0,0,0,0};\
            __builtin_amdgcn_s_setprio(1);                                       \
            aR = MFMA(aR, Ah0, BRh0); aR = MFMA(aR, Ah0, BRl0);                  \
            aR = MFMA(aR, Al0, BRh0); aR = MFMA(aR, Ah1, BRh1);                  \
            aR = MFMA(aR, Ah1, BRl1); aR = MFMA(aR, Al1, BRh1);                  \
            aR = MFMA(aR, Ah2, BRh2); aR = MFMA(aR, Ah3, BRh3);                  \
            aZ = MFMA(aZ, Ah0, BZh0); aZ = MFMA(aZ, Ah0, BZl0);                  \
            aZ = MFMA(aZ, Al0, BZh0); aZ = MFMA(aZ, Ah1, BZh1);                  \
            aZ = MFMA(aZ, Ah1, BZl1); aZ = MFMA(aZ, Al1, BZh1);                  \
            aZ = MFMA(aZ, Ah2, BZh2); aZ = MFMA(aZ, Ah3, BZh3);                  \
            aI = MFMA(aI, Ah0, BIh0); aI = MFMA(aI, Ah0, BIl0);                  \
            aI = MFMA(aI, Al0, BIh0); aI = MFMA(aI, Ah1, BIh1);                  \
            aI = MFMA(aI, Ah1, BIl1); aI = MFMA(aI, Al1, BIh1);                  \
            aH = MFMA(aH, Ah2, BHh0); aH = MFMA(aH, Ah3, BHh1);                  \
            __builtin_amdgcn_s_setprio(0);                                       \
            _Pragma("unroll")                                                    \
            for (int r = 0; r < 4; ++r) {                                        \
                int  eloc = mt * 16 + rowg * 4 + r;                              \
                long ev   = base + (CB) + eloc;                                  \
                if (full || ev < n) {                                            \
                    float rr = sigmoidf_(aR[r] + bR);                            \
                    float zz = sigmoidf_(aZ[r] + bZ);                            \
                    float nn = tanh_fast(aI[r] + bIN + rr * (aH[r] + bHN));      \
                    float hv = (float)xhh[eloc][64 + d];                         \
                    float o  = (1.f - zz) * nn + zz * hv;                        \
                    out0[(size_t)ev * 64 + d] = o;                               \
                    if (swin[(CB) + eloc])                                       \
                        out1[(size_t)sid[(CB) + eloc] * 64 + d] = o;             \
                }                                                                \
            }                                                                    \
        }                                                                        \
    }

    // ---- chunk0 MFMA + epilogue (chunk1 gathers in flight underneath) ----
    DO_MFMA_EPI(0)
    __syncthreads();

    // ---- chunk1 convert (loads landed long ago) + MFMA ----
    CONV_WRITE(x0, h0, db0, 0)
    CONV_WRITE(x1, h1, db1, 1)
    CONV_WRITE(x2, h2, db2, 2)
    CONV_WRITE(x3, h3, db3, 3)
    __syncthreads();
    DO_MFMA_EPI(64)

    #undef CONV_WRITE
    #undef DO_MFMA_EPI
}

// ---------------- fused tail: loser-row copy + timestamp scatter ----------------
__global__ void k_tail(float* out2,
                       const f32x4* __restrict__ mem4,
                       f32x4* __restrict__ out14,
                       const float* __restrict__ ts,
                       const float* __restrict__ lut,
                       const int* __restrict__ winner,
                       int num_nodes)
{
    int idx = blockIdx.x * blockDim.x + threadIdx.x;
    if (idx >= num_nodes * 16) return;
    int nidx = idx >> 4;
    int c    = idx & 15;
    int wv = winner[nidx];
    if (wv < 0) {
        f32x4 v = __builtin_nontemporal_load(&mem4[idx]);
        __builtin_nontemporal_store(v, &out14[idx]);
    }
    if (c == 0) out2[nidx] = (wv >= 0) ? ts[wv] : lut[nidx];
}

extern "C" void kernel_launch(void* const* d_in, const int* in_sizes, int n_in,
                              void* d_out, int out_size, void* d_ws, size_t ws_size,
                              hipStream_t stream) {
    const int*   ids = (const int*)  d_in[0];
    const float* emb = (const float*)d_in[1];
    const float* ts  = (const float*)d_in[2];
    const float* mem = (const float*)d_in[3];
    const float* lut = (const float*)d_in[4];
    const float* Wt  = (const float*)d_in[5];
    const float* bt  = (const float*)d_in[6];
    const float* Wih = (const float*)d_in[7];
    const float* Whh = (const float*)d_in[8];
    const float* bih = (const float*)d_in[9];
    const float* bhh = (const float*)d_in[10];

    const int N         = in_sizes[0];
    const int NUM_NODES = in_sizes[4];

    float* out0 = (float*)d_out;                    // [N,64]
    float* out1 = out0 + (size_t)N * DD;            // [NUM_NODES,64]
    float* out2 = out1 + (size_t)NUM_NODES * DD;    // [NUM_NODES]

    _Float16* bfragH = (_Float16*)d_ws;                          // 64 KB
    _Float16* bfragL = bfragH + 64 * 64 * 8;                     // 64 KB
    float*    dtw    = (float*)((char*)d_ws + 128 * 1024);       // N*4 B
    int*      winner = (int*)((char*)d_ws + 128 * 1024 + (size_t)N * 4);  // NUM_NODES*4 B

    int initBlocks = (NUM_NODES + 255) / 256;
    k_prep_init<<<16 + initBlocks, 256, 0, stream>>>(Wih, Whh, bfragH, bfragL,
                                                     winner, NUM_NODES);
    k_vote_dt<<<(N + 255) / 256, 256, 0, stream>>>(ids, ts, lut, winner, dtw, N);

    int gruBlocks = (N + 127) / 128;
    k_gru<<<gruBlocks, 256, 0, stream>>>(ids, emb, mem, Wt, bt, bih, bhh,
                                         bfragH, bfragL, winner, dtw, out0, out1, N);

    long vec = (long)NUM_NODES * 16;
    k_tail<<<(int)((vec + 255) / 256), 256, 0, stream>>>(
        out2, (const f32x4*)mem, (f32x4*)out1, ts, lut, winner, NUM_NODES);
}

// Round 15
// 225.673 us; speedup vs baseline: 1.2718x; 1.2718x over previous
//
#include <hip/hip_runtime.h>
#include <cstdint>
#include <cstddef>

#define DD 64

typedef float    f32x4  __attribute__((ext_vector_type(4)));
typedef _Float16 f16x8  __attribute__((ext_vector_type(8)));
typedef _Float16 f16x4  __attribute__((ext_vector_type(4)));

__device__ __forceinline__ float sigmoidf_(float x) {
    return 1.0f / (1.0f + __expf(-x));
}
__device__ __forceinline__ float tanh_fast(float x) {
    float ax = fabsf(x);
    float t = 1.0f - 2.0f / (1.0f + __expf(2.0f * ax));
    return copysignf(t, x);
}
__device__ __forceinline__ f32x4 MFMA(f32x4 c, f16x8 a, f16x8 b) {
    return __builtin_amdgcn_mfma_f32_16x16x32_f16(a, b, c, 0, 0, 0);
}

// ---- fused prep: B-hi fragments (blocks 0..15) + rank-1 u/c (block 16) + winner init ----
// B[128][256]: cols 0..63 r (K: x|h), 64..127 z, 128..191 i_n (x only), 192..255 h_n (h only).
// Fragment f = g*4+s; lane l holds B[s*32+(l>>4)*8+j][g*16+(l&15)], j=0..7. fp16 HI only —
// the rank-1 time term carries the magnitude, so no lo-correction plane is needed.
__global__ void k_prep_init(const float* __restrict__ Wih, const float* __restrict__ Whh,
                            const float* __restrict__ Wt, const float* __restrict__ bt,
                            _Float16* __restrict__ bhi, float* __restrict__ u, float* __restrict__ c,
                            int* __restrict__ winner, int num_nodes)
{
    if (blockIdx.x < 16) {
        int f = blockIdx.x * 4 + (threadIdx.x >> 6);   // 0..63
        int l = threadIdx.x & 63;
        int g = f >> 2, s = f & 3;
        int cc = g * 16 + (l & 15);
        int grp = cc >> 6, dd = cc & 63;
        int kbase = s * 32 + (l >> 4) * 8;
        int row = (grp == 0) ? dd : (grp == 1) ? 64 + dd : 128 + dd;

        f16x8 hv;
        for (int j = 0; j < 8; ++j) {
            int k = kbase + j;
            float v;
            if (grp <= 1)      v = (k < 64) ? Wih[row * 64 + k] : Whh[row * 64 + (k - 64)];
            else if (grp == 2) v = (k < 64) ? Wih[row * 64 + k] : 0.0f;
            else               v = (k < 64) ? 0.0f : Whh[row * 64 + (k - 64)];
            hv[j] = (_Float16)v;
        }
        ((f16x8*)bhi)[(size_t)f * 64 + l] = hv;
    } else if (blockIdx.x == 16) {
        // u[row] = Wih[row,:] @ Wt ; c[row] = Wih[row,:] @ bt  (row 0..191)
        int t = threadIdx.x;
        if (t < 192) {
            float su = 0.f, sc = 0.f;
            for (int k = 0; k < 64; ++k) {
                float wv = Wih[t * 64 + k];
                su = fmaf(wv, Wt[k], su);
                sc = fmaf(wv, bt[k], sc);
            }
            u[t] = su;
            c[t] = sc;
        }
    } else {
        int i = (int)(blockIdx.x - 17) * 256 + threadIdx.x;
        if (i < num_nodes) winner[i] = -1;
    }
}

// ---------------- vote + dt precompute ----------------
__global__ void k_vote_dt(const int* __restrict__ ids, const float* __restrict__ ts,
                          const float* __restrict__ lut, int* __restrict__ winner,
                          float* __restrict__ dtw, int n) {
    int i = blockIdx.x * blockDim.x + threadIdx.x;
    if (i < n) {
        int id = ids[i];
        atomicMax(&winner[id], i);
        dtw[i] = ts[i] - lut[id];
    }
}

// ---------------- main GRU kernel: rank-1 time term, single fp16 plane ----------------
// A = [emb_fp16 | h_fp16]; gate preact = MFMA(A,B) + dt*u[g] + C[g] in epilogue.
// emb staging is independent of ids -> issues before the scalar chase.
__global__ __launch_bounds__(256, 4) void k_gru(
    const int* __restrict__ ids,
    const float* __restrict__ emb,
    const float* __restrict__ mem,
    const float* __restrict__ bih,
    const float* __restrict__ bhh,
    const _Float16* __restrict__ bhi,
    const float* __restrict__ u,
    const float* __restrict__ c,
    const int* __restrict__ winner,
    const float* __restrict__ dtw,
    float* __restrict__ out0,
    float* __restrict__ out1,
    int n)
{
    __shared__ _Float16 xhh[64][136];   // [event][k]: k<64 emb_fp16, k>=64 h_fp16
    __shared__ float sdt[64];
    __shared__ int sid[64];
    __shared__ int swin[64];

    const int w    = threadIdx.x >> 6;
    const int l    = threadIdx.x & 63;
    const int col  = l & 15;
    const int rowg = l >> 4;
    const int d    = w * 16 + col;

    const long base = (long)blockIdx.x * 64;
    const bool full = (base + 64 <= (long)n);

    const f32x4* emb4 = (const f32x4*)emb;
    const f32x4* mem4 = (const f32x4*)mem;

    // ---- emb loads: fully independent, issue first ----
    f32x4 xv0, xv1, xv2, xv3;
    {
        const size_t e0 = (size_t)(base + w * 16 + 0 * 4 + rowg) * 16 + col;
        const size_t e1 = (size_t)(base + w * 16 + 1 * 4 + rowg) * 16 + col;
        const size_t e2 = (size_t)(base + w * 16 + 2 * 4 + rowg) * 16 + col;
        const size_t e3 = (size_t)(base + w * 16 + 3 * 4 + rowg) * 16 + col;
        if (full) {
            xv0 = __builtin_nontemporal_load(&emb4[e0]);
            xv1 = __builtin_nontemporal_load(&emb4[e1]);
            xv2 = __builtin_nontemporal_load(&emb4[e2]);
            xv3 = __builtin_nontemporal_load(&emb4[e3]);
        } else {
            f32x4 z = {0.f, 0.f, 0.f, 0.f};
            xv0 = xv1 = xv2 = xv3 = z;
            if (base + w * 16 + 0 * 4 + rowg < n) xv0 = emb4[e0];
            if (base + w * 16 + 1 * 4 + rowg < n) xv1 = emb4[e1];
            if (base + w * 16 + 2 * 4 + rowg < n) xv2 = emb4[e2];
            if (base + w * 16 + 3 * 4 + rowg < n) xv3 = emb4[e3];
        }
    }

    // ---- phase A: coalesced ids/dtw + winner gather (winner used in epilogue only) ----
    const int  e16 = w * 16 + col;
    const long evA = base + e16;
    int idA = 0, winA = 0; float dtA = 0.f;
    if (full || evA < n) {
        idA  = ids[evA];
        dtA  = dtw[evA];
        winA = (winner[idA] == (int)evA) ? 1 : 0;
    }
    if (l < 16) { sid[e16] = idA; swin[e16] = winA; sdt[e16] = dtA; }

    // ---- mem gathers ----
    f32x4 hv0, hv1, hv2, hv3;
    {
        int i0 = __shfl(idA, 0 * 4 + rowg), i1 = __shfl(idA, 1 * 4 + rowg);
        int i2 = __shfl(idA, 2 * 4 + rowg), i3 = __shfl(idA, 3 * 4 + rowg);
        if (full) {
            hv0 = mem4[(size_t)i0 * 16 + col];
            hv1 = mem4[(size_t)i1 * 16 + col];
            hv2 = mem4[(size_t)i2 * 16 + col];
            hv3 = mem4[(size_t)i3 * 16 + col];
        } else {
            f32x4 z = {0.f, 0.f, 0.f, 0.f};
            hv0 = hv1 = hv2 = hv3 = z;
            if (base + w * 16 + 0 * 4 + rowg < n) hv0 = mem4[(size_t)i0 * 16 + col];
            if (base + w * 16 + 1 * 4 + rowg < n) hv1 = mem4[(size_t)i1 * 16 + col];
            if (base + w * 16 + 2 * 4 + rowg < n) hv2 = mem4[(size_t)i2 * 16 + col];
            if (base + w * 16 + 3 * 4 + rowg < n) hv3 = mem4[(size_t)i3 * 16 + col];
        }
    }

    // ---- convert + LDS write (no dt math, no split) ----
    #define CONV_WRITE(XV, HV, IT)                                               \
    {                                                                            \
        int r = w * 16 + (IT) * 4 + rowg;                                        \
        f16x4 xh, hh;                                                            \
        xh[0] = (_Float16)(XV).x; xh[1] = (_Float16)(XV).y;                      \
        xh[2] = (_Float16)(XV).z; xh[3] = (_Float16)(XV).w;                      \
        hh[0] = (_Float16)(HV).x; hh[1] = (_Float16)(HV).y;                      \
        hh[2] = (_Float16)(HV).z; hh[3] = (_Float16)(HV).w;                      \
        *(f16x4*)&xhh[r][col * 4]      = xh;                                     \
        *(f16x4*)&xhh[r][64 + col * 4] = hh;                                     \
    }
    CONV_WRITE(xv0, hv0, 0)
    CONV_WRITE(xv1, hv1, 1)
    CONV_WRITE(xv2, hv2, 2)
    CONV_WRITE(xv3, hv3, 3)
    #undef CONV_WRITE

    // ---- B fragments (L2-resident): 12 per wave ----
    const f16x8* H = (const f16x8*)bhi;
    f16x8 BRh0 = H[(size_t)(w * 4 + 0) * 64 + l];
    f16x8 BRh1 = H[(size_t)(w * 4 + 1) * 64 + l];
    f16x8 BRh2 = H[(size_t)(w * 4 + 2) * 64 + l];
    f16x8 BRh3 = H[(size_t)(w * 4 + 3) * 64 + l];
    f16x8 BZh0 = H[(size_t)((4 + w) * 4 + 0) * 64 + l];
    f16x8 BZh1 = H[(size_t)((4 + w) * 4 + 1) * 64 + l];
    f16x8 BZh2 = H[(size_t)((4 + w) * 4 + 2) * 64 + l];
    f16x8 BZh3 = H[(size_t)((4 + w) * 4 + 3) * 64 + l];
    f16x8 BIh0 = H[(size_t)((8 + w) * 4 + 0) * 64 + l];
    f16x8 BIh1 = H[(size_t)((8 + w) * 4 + 1) * 64 + l];
    f16x8 BHh0 = H[(size_t)((12 + w) * 4 + 2) * 64 + l];
    f16x8 BHh1 = H[(size_t)((12 + w) * 4 + 3) * 64 + l];

    // per-lane rank-1 + bias constants
    const float uR = u[d],        uZ = u[64 + d],  uI = u[128 + d];
    const float CR = c[d]        + bih[d]        + bhh[d];
    const float CZ = c[64 + d]   + bih[64 + d]   + bhh[64 + d];
    const float CI = c[128 + d]  + bih[128 + d];
    const float bHN = bhh[128 + d];

    __syncthreads();

    // ---- 4 M-tiles of 16 events each: 12 MFMA per tile ----
    #pragma unroll
    for (int mt = 0; mt < 4; ++mt) {
        const int arow = mt * 16 + col;
        const int k0   = rowg * 8;
        f16x8 Ah0 = *(const f16x8*)&xhh[arow][0 * 32 + k0];
        f16x8 Ah1 = *(const f16x8*)&xhh[arow][1 * 32 + k0];
        f16x8 Ah2 = *(const f16x8*)&xhh[arow][2 * 32 + k0];
        f16x8 Ah3 = *(const f16x8*)&xhh[arow][3 * 32 + k0];

        f32x4 aR = {0,0,0,0}, aZ = {0,0,0,0}, aI = {0,0,0,0}, aH = {0,0,0,0};
        __builtin_amdgcn_s_setprio(1);
        aR = MFMA(aR, Ah0, BRh0); aR = MFMA(aR, Ah1, BRh1);
        aR = MFMA(aR, Ah2, BRh2); aR = MFMA(aR, Ah3, BRh3);
        aZ = MFMA(aZ, Ah0, BZh0); aZ = MFMA(aZ, Ah1, BZh1);
        aZ = MFMA(aZ, Ah2, BZh2); aZ = MFMA(aZ, Ah3, BZh3);
        aI = MFMA(aI, Ah0, BIh0); aI = MFMA(aI, Ah1, BIh1);
        aH = MFMA(aH, Ah2, BHh0); aH = MFMA(aH, Ah3, BHh1);
        __builtin_amdgcn_s_setprio(0);

        #pragma unroll
        for (int r = 0; r < 4; ++r) {
            int  eloc = mt * 16 + rowg * 4 + r;
            long ev   = base + eloc;
            if (full || ev < n) {
                float dt = sdt[eloc];
                float rr = sigmoidf_(aR[r] + fmaf(dt, uR, CR));
                float zz = sigmoidf_(aZ[r] + fmaf(dt, uZ, CZ));
                float nn = tanh_fast(aI[r] + fmaf(dt, uI, CI) + rr * (aH[r] + bHN));
                float hv = (float)xhh[eloc][64 + d];
                float o  = (1.f - zz) * nn + zz * hv;
                out0[(size_t)ev * 64 + d] = o;
                if (swin[eloc])
                    out1[(size_t)sid[eloc] * 64 + d] = o;
            }
        }
    }
}

// ---------------- fused tail: loser-row copy + timestamp scatter ----------------
// winner stored IN out2; each 16-thread group reads its node's winner, then lane
// c==0 overwrites that same slot (read-before-write within the wave -> safe).
__global__ void k_tail(float* out2,
                       const f32x4* __restrict__ mem4,
                       f32x4* __restrict__ out14,
                       const float* __restrict__ ts,
                       const float* __restrict__ lut,
                       int num_nodes)
{
    int idx = blockIdx.x * blockDim.x + threadIdx.x;
    if (idx >= num_nodes * 16) return;
    int nidx = idx >> 4;
    int cc   = idx & 15;
    int wv = reinterpret_cast<const int*>(out2)[nidx];
    if (wv < 0) {
        f32x4 v = __builtin_nontemporal_load(&mem4[idx]);
        __builtin_nontemporal_store(v, &out14[idx]);
    }
    if (cc == 0) out2[nidx] = (wv >= 0) ? ts[wv] : lut[nidx];
}

extern "C" void kernel_launch(void* const* d_in, const int* in_sizes, int n_in,
                              void* d_out, int out_size, void* d_ws, size_t ws_size,
                              hipStream_t stream) {
    const int*   ids = (const int*)  d_in[0];
    const float* emb = (const float*)d_in[1];
    const float* ts  = (const float*)d_in[2];
    const float* mem = (const float*)d_in[3];
    const float* lut = (const float*)d_in[4];
    const float* Wt  = (const float*)d_in[5];
    const float* bt  = (const float*)d_in[6];
    const float* Wih = (const float*)d_in[7];
    const float* Whh = (const float*)d_in[8];
    const float* bih = (const float*)d_in[9];
    const float* bhh = (const float*)d_in[10];

    const int N         = in_sizes[0];
    const int NUM_NODES = in_sizes[4];

    float* out0 = (float*)d_out;                    // [N,64]
    float* out1 = out0 + (size_t)N * DD;            // [NUM_NODES,64]
    float* out2 = out1 + (size_t)NUM_NODES * DD;    // [NUM_NODES]
    int*   winner = (int*)out2;                     // reuse out2 region (r13 scheme)

    _Float16* bfragH = (_Float16*)d_ws;                          // 64 KB
    float*    uvec   = (float*)((char*)d_ws + 64 * 1024);        // 192 f
    float*    cvec   = uvec + 192;                               // 192 f
    float*    dtw    = (float*)((char*)d_ws + 72 * 1024);        // N * 4 B

    int initBlocks = (NUM_NODES + 255) / 256;
    k_prep_init<<<17 + initBlocks, 256, 0, stream>>>(Wih, Whh, Wt, bt, bfragH,
                                                     uvec, cvec, winner, NUM_NODES);
    k_vote_dt<<<(N + 255) / 256, 256, 0, stream>>>(ids, ts, lut, winner, dtw, N);

    int nchunks = (N + 63) / 64;
    k_gru<<<nchunks, 256, 0, stream>>>(ids, emb, mem, bih, bhh, bfragH,
                                       uvec, cvec, winner, dtw, out0, out1, N);

    long vec = (long)NUM_NODES * 16;
    k_tail<<<(int)((vec + 255) / 256), 256, 0, stream>>>(
        out2, (const f32x4*)mem, (f32x4*)out1, ts, lut, NUM_NODES);
}

// Round 16
// 216.608 us; speedup vs baseline: 1.3250x; 1.0419x over previous
//
#include <hip/hip_runtime.h>
#include <cstdint>
#include <cstddef>

#define DD 64

typedef float    f32x4  __attribute__((ext_vector_type(4)));
typedef _Float16 f16x8  __attribute__((ext_vector_type(8)));
typedef _Float16 f16x4  __attribute__((ext_vector_type(4)));

__device__ __forceinline__ float sigmoidf_(float x) {
    return 1.0f / (1.0f + __expf(-x));
}
__device__ __forceinline__ float tanh_fast(float x) {
    float ax = fabsf(x);
    float t = 1.0f - 2.0f / (1.0f + __expf(2.0f * ax));
    return copysignf(t, x);
}
__device__ __forceinline__ f32x4 MFMA(f32x4 c, f16x8 a, f16x8 b) {
    return __builtin_amdgcn_mfma_f32_16x16x32_f16(a, b, c, 0, 0, 0);
}

// ---- fused prep: B-hi fragments (blocks 0..15) + rank-1 u/c (block 16) + winner init ----
// B[128][256]: cols 0..63 r (K: x|h), 64..127 z, 128..191 i_n (x only), 192..255 h_n (h only).
// Fragment f = g*4+s; lane l holds B[s*32+(l>>4)*8+j][g*16+(l&15)], j=0..7. fp16 HI only —
// the rank-1 time term carries the magnitude, so no lo-correction plane is needed.
__global__ void k_prep_init(const float* __restrict__ Wih, const float* __restrict__ Whh,
                            const float* __restrict__ Wt, const float* __restrict__ bt,
                            _Float16* __restrict__ bhi, float* __restrict__ u, float* __restrict__ c,
                            int* __restrict__ winner, int num_nodes)
{
    if (blockIdx.x < 16) {
        int f = blockIdx.x * 4 + (threadIdx.x >> 6);   // 0..63
        int l = threadIdx.x & 63;
        int g = f >> 2, s = f & 3;
        int cc = g * 16 + (l & 15);
        int grp = cc >> 6, dd = cc & 63;
        int kbase = s * 32 + (l >> 4) * 8;
        int row = (grp == 0) ? dd : (grp == 1) ? 64 + dd : 128 + dd;

        f16x8 hv;
        for (int j = 0; j < 8; ++j) {
            int k = kbase + j;
            float v;
            if (grp <= 1)      v = (k < 64) ? Wih[row * 64 + k] : Whh[row * 64 + (k - 64)];
            else if (grp == 2) v = (k < 64) ? Wih[row * 64 + k] : 0.0f;
            else               v = (k < 64) ? 0.0f : Whh[row * 64 + (k - 64)];
            hv[j] = (_Float16)v;
        }
        ((f16x8*)bhi)[(size_t)f * 64 + l] = hv;
    } else if (blockIdx.x == 16) {
        // u[row] = Wih[row,:] @ Wt ; c[row] = Wih[row,:] @ bt  (row 0..191)
        int t = threadIdx.x;
        if (t < 192) {
            float su = 0.f, sc = 0.f;
            for (int k = 0; k < 64; ++k) {
                float wv = Wih[t * 64 + k];
                su = fmaf(wv, Wt[k], su);
                sc = fmaf(wv, bt[k], sc);
            }
            u[t] = su;
            c[t] = sc;
        }
    } else {
        int i = (int)(blockIdx.x - 17) * 256 + threadIdx.x;
        if (i < num_nodes) winner[i] = -1;
    }
}

// ---------------- vote + dt precompute ----------------
__global__ void k_vote_dt(const int* __restrict__ ids, const float* __restrict__ ts,
                          const float* __restrict__ lut, int* __restrict__ winner,
                          float* __restrict__ dtw, int n) {
    int i = blockIdx.x * blockDim.x + threadIdx.x;
    if (i < n) {
        int id = ids[i];
        atomicMax(&winner[id], i);
        dtw[i] = ts[i] - lut[id];
    }
}

// ---------------- main GRU kernel: rank-1, out0 only (winner scatter moved to tail) ----------------
// A = [emb_fp16 | h_fp16]; gate preact = MFMA(A,B) + dt*u[g] + C[g] in epilogue.
// Phase A is now ids+dtw (coalesced) -> shfl -> mem gather: single random hop.
__global__ __launch_bounds__(256, 4) void k_gru(
    const int* __restrict__ ids,
    const float* __restrict__ emb,
    const float* __restrict__ mem,
    const float* __restrict__ bih,
    const float* __restrict__ bhh,
    const _Float16* __restrict__ bhi,
    const float* __restrict__ u,
    const float* __restrict__ c,
    const float* __restrict__ dtw,
    float* __restrict__ out0,
    int n)
{
    __shared__ _Float16 xhh[64][136];   // [event][k]: k<64 emb_fp16, k>=64 h_fp16
    __shared__ float sdt[64];

    const int w    = threadIdx.x >> 6;
    const int l    = threadIdx.x & 63;
    const int col  = l & 15;
    const int rowg = l >> 4;
    const int d    = w * 16 + col;

    const long base = (long)blockIdx.x * 64;
    const bool full = (base + 64 <= (long)n);

    const f32x4* emb4 = (const f32x4*)emb;
    const f32x4* mem4 = (const f32x4*)mem;

    // ---- emb loads: fully independent, issue first ----
    f32x4 xv0, xv1, xv2, xv3;
    {
        const size_t e0 = (size_t)(base + w * 16 + 0 * 4 + rowg) * 16 + col;
        const size_t e1 = (size_t)(base + w * 16 + 1 * 4 + rowg) * 16 + col;
        const size_t e2 = (size_t)(base + w * 16 + 2 * 4 + rowg) * 16 + col;
        const size_t e3 = (size_t)(base + w * 16 + 3 * 4 + rowg) * 16 + col;
        if (full) {
            xv0 = __builtin_nontemporal_load(&emb4[e0]);
            xv1 = __builtin_nontemporal_load(&emb4[e1]);
            xv2 = __builtin_nontemporal_load(&emb4[e2]);
            xv3 = __builtin_nontemporal_load(&emb4[e3]);
        } else {
            f32x4 z = {0.f, 0.f, 0.f, 0.f};
            xv0 = xv1 = xv2 = xv3 = z;
            if (base + w * 16 + 0 * 4 + rowg < n) xv0 = emb4[e0];
            if (base + w * 16 + 1 * 4 + rowg < n) xv1 = emb4[e1];
            if (base + w * 16 + 2 * 4 + rowg < n) xv2 = emb4[e2];
            if (base + w * 16 + 3 * 4 + rowg < n) xv3 = emb4[e3];
        }
    }

    // ---- phase A: coalesced ids + dtw only ----
    const int  e16 = w * 16 + col;
    const long evA = base + e16;
    int idA = 0; float dtA = 0.f;
    if (full || evA < n) {
        idA = ids[evA];
        dtA = dtw[evA];
    }
    if (l < 16) sdt[e16] = dtA;

    // ---- mem gathers (the one random hop) ----
    f32x4 hv0, hv1, hv2, hv3;
    {
        int i0 = __shfl(idA, 0 * 4 + rowg), i1 = __shfl(idA, 1 * 4 + rowg);
        int i2 = __shfl(idA, 2 * 4 + rowg), i3 = __shfl(idA, 3 * 4 + rowg);
        if (full) {
            hv0 = mem4[(size_t)i0 * 16 + col];
            hv1 = mem4[(size_t)i1 * 16 + col];
            hv2 = mem4[(size_t)i2 * 16 + col];
            hv3 = mem4[(size_t)i3 * 16 + col];
        } else {
            f32x4 z = {0.f, 0.f, 0.f, 0.f};
            hv0 = hv1 = hv2 = hv3 = z;
            if (base + w * 16 + 0 * 4 + rowg < n) hv0 = mem4[(size_t)i0 * 16 + col];
            if (base + w * 16 + 1 * 4 + rowg < n) hv1 = mem4[(size_t)i1 * 16 + col];
            if (base + w * 16 + 2 * 4 + rowg < n) hv2 = mem4[(size_t)i2 * 16 + col];
            if (base + w * 16 + 3 * 4 + rowg < n) hv3 = mem4[(size_t)i3 * 16 + col];
        }
    }

    // ---- convert + LDS write ----
    #define CONV_WRITE(XV, HV, IT)                                               \
    {                                                                            \
        int r = w * 16 + (IT) * 4 + rowg;                                        \
        f16x4 xh, hh;                                                            \
        xh[0] = (_Float16)(XV).x; xh[1] = (_Float16)(XV).y;                      \
        xh[2] = (_Float16)(XV).z; xh[3] = (_Float16)(XV).w;                      \
        hh[0] = (_Float16)(HV).x; hh[1] = (_Float16)(HV).y;                      \
        hh[2] = (_Float16)(HV).z; hh[3] = (_Float16)(HV).w;                      \
        *(f16x4*)&xhh[r][col * 4]      = xh;                                     \
        *(f16x4*)&xhh[r][64 + col * 4] = hh;                                     \
    }
    CONV_WRITE(xv0, hv0, 0)
    CONV_WRITE(xv1, hv1, 1)
    CONV_WRITE(xv2, hv2, 2)
    CONV_WRITE(xv3, hv3, 3)
    #undef CONV_WRITE

    // ---- B fragments (L2-resident): 12 per wave ----
    const f16x8* H = (const f16x8*)bhi;
    f16x8 BRh0 = H[(size_t)(w * 4 + 0) * 64 + l];
    f16x8 BRh1 = H[(size_t)(w * 4 + 1) * 64 + l];
    f16x8 BRh2 = H[(size_t)(w * 4 + 2) * 64 + l];
    f16x8 BRh3 = H[(size_t)(w * 4 + 3) * 64 + l];
    f16x8 BZh0 = H[(size_t)((4 + w) * 4 + 0) * 64 + l];
    f16x8 BZh1 = H[(size_t)((4 + w) * 4 + 1) * 64 + l];
    f16x8 BZh2 = H[(size_t)((4 + w) * 4 + 2) * 64 + l];
    f16x8 BZh3 = H[(size_t)((4 + w) * 4 + 3) * 64 + l];
    f16x8 BIh0 = H[(size_t)((8 + w) * 4 + 0) * 64 + l];
    f16x8 BIh1 = H[(size_t)((8 + w) * 4 + 1) * 64 + l];
    f16x8 BHh0 = H[(size_t)((12 + w) * 4 + 2) * 64 + l];
    f16x8 BHh1 = H[(size_t)((12 + w) * 4 + 3) * 64 + l];

    // per-lane rank-1 + bias constants
    const float uR = u[d],        uZ = u[64 + d],  uI = u[128 + d];
    const float CR = c[d]        + bih[d]        + bhh[d];
    const float CZ = c[64 + d]   + bih[64 + d]   + bhh[64 + d];
    const float CI = c[128 + d]  + bih[128 + d];
    const float bHN = bhh[128 + d];

    __syncthreads();

    // ---- 4 M-tiles of 16 events each: 12 MFMA per tile ----
    #pragma unroll
    for (int mt = 0; mt < 4; ++mt) {
        const int arow = mt * 16 + col;
        const int k0   = rowg * 8;
        f16x8 Ah0 = *(const f16x8*)&xhh[arow][0 * 32 + k0];
        f16x8 Ah1 = *(const f16x8*)&xhh[arow][1 * 32 + k0];
        f16x8 Ah2 = *(const f16x8*)&xhh[arow][2 * 32 + k0];
        f16x8 Ah3 = *(const f16x8*)&xhh[arow][3 * 32 + k0];

        f32x4 aR = {0,0,0,0}, aZ = {0,0,0,0}, aI = {0,0,0,0}, aH = {0,0,0,0};
        __builtin_amdgcn_s_setprio(1);
        aR = MFMA(aR, Ah0, BRh0); aR = MFMA(aR, Ah1, BRh1);
        aR = MFMA(aR, Ah2, BRh2); aR = MFMA(aR, Ah3, BRh3);
        aZ = MFMA(aZ, Ah0, BZh0); aZ = MFMA(aZ, Ah1, BZh1);
        aZ = MFMA(aZ, Ah2, BZh2); aZ = MFMA(aZ, Ah3, BZh3);
        aI = MFMA(aI, Ah0, BIh0); aI = MFMA(aI, Ah1, BIh1);
        aH = MFMA(aH, Ah2, BHh0); aH = MFMA(aH, Ah3, BHh1);
        __builtin_amdgcn_s_setprio(0);

        #pragma unroll
        for (int r = 0; r < 4; ++r) {
            int  eloc = mt * 16 + rowg * 4 + r;
            long ev   = base + eloc;
            if (full || ev < n) {
                float dt = sdt[eloc];
                float rr = sigmoidf_(aR[r] + fmaf(dt, uR, CR));
                float zz = sigmoidf_(aZ[r] + fmaf(dt, uZ, CZ));
                float nn = tanh_fast(aI[r] + fmaf(dt, uI, CI) + rr * (aH[r] + bHN));
                float hv = (float)xhh[eloc][64 + d];
                float o  = (1.f - zz) * nn + zz * hv;
                out0[(size_t)ev * 64 + d] = o;
            }
        }
    }
}

// ---------------- tail: out1 assembly (gather) + timestamp scatter ----------------
// out1[node] = winner>=0 ? out0[winner[node]] (L2/L3-hot gather) : mem[node];
// out2[node] = winner>=0 ? ts[winner] : lut[node].
// winner stored IN out2; all 16 readers of a node are in the writer's wave -> safe.
__global__ void k_tail(float* out2,
                       const f32x4* __restrict__ mem4,
                       const f32x4* __restrict__ out04,
                       f32x4* __restrict__ out14,
                       const float* __restrict__ ts,
                       const float* __restrict__ lut,
                       int num_nodes)
{
    int idx = blockIdx.x * blockDim.x + threadIdx.x;
    if (idx >= num_nodes * 16) return;
    int nidx = idx >> 4;
    int cc   = idx & 15;
    int wv = reinterpret_cast<const int*>(out2)[nidx];
    f32x4 v;
    if (wv >= 0) {
        v = out04[(size_t)wv * 16 + cc];                       // gather, L2/L3-hot
    } else {
        v = __builtin_nontemporal_load(&mem4[idx]);            // streaming copy
    }
    __builtin_nontemporal_store(v, &out14[idx]);               // coalesced full rows
    if (cc == 0) out2[nidx] = (wv >= 0) ? ts[wv] : lut[nidx];
}

extern "C" void kernel_launch(void* const* d_in, const int* in_sizes, int n_in,
                              void* d_out, int out_size, void* d_ws, size_t ws_size,
                              hipStream_t stream) {
    const int*   ids = (const int*)  d_in[0];
    const float* emb = (const float*)d_in[1];
    const float* ts  = (const float*)d_in[2];
    const float* mem = (const float*)d_in[3];
    const float* lut = (const float*)d_in[4];
    const float* Wt  = (const float*)d_in[5];
    const float* bt  = (const float*)d_in[6];
    const float* Wih = (const float*)d_in[7];
    const float* Whh = (const float*)d_in[8];
    const float* bih = (const float*)d_in[9];
    const float* bhh = (const float*)d_in[10];

    const int N         = in_sizes[0];
    const int NUM_NODES = in_sizes[4];

    float* out0 = (float*)d_out;                    // [N,64]
    float* out1 = out0 + (size_t)N * DD;            // [NUM_NODES,64]
    float* out2 = out1 + (size_t)NUM_NODES * DD;    // [NUM_NODES]
    int*   winner = (int*)out2;                     // winner lives in out2 region

    _Float16* bfragH = (_Float16*)d_ws;                          // 64 KB
    float*    uvec   = (float*)((char*)d_ws + 64 * 1024);        // 192 f
    float*    cvec   = uvec + 192;                               // 192 f
    float*    dtw    = (float*)((char*)d_ws + 72 * 1024);        // N * 4 B

    int initBlocks = (NUM_NODES + 255) / 256;
    k_prep_init<<<17 + initBlocks, 256, 0, stream>>>(Wih, Whh, Wt, bt, bfragH,
                                                     uvec, cvec, winner, NUM_NODES);
    k_vote_dt<<<(N + 255) / 256, 256, 0, stream>>>(ids, ts, lut, winner, dtw, N);

    int nchunks = (N + 63) / 64;
    k_gru<<<nchunks, 256, 0, stream>>>(ids, emb, mem, bih, bhh, bfragH,
                                       uvec, cvec, dtw, out0, N);

    long vec = (long)NUM_NODES * 16;
    k_tail<<<(int)((vec + 255) / 256), 256, 0, stream>>>(
        out2, (const f32x4*)mem, (const f32x4*)out0, (f32x4*)out1, ts, lut, NUM_NODES);
}

// Round 17
// 201.880 us; speedup vs baseline: 1.4217x; 1.0730x over previous
//
#include <hip/hip_runtime.h>
#include <cstdint>
#include <cstddef>

#define DD 64

typedef float    f32x4  __attribute__((ext_vector_type(4)));
typedef _Float16 f16x8  __attribute__((ext_vector_type(8)));
typedef _Float16 f16x4  __attribute__((ext_vector_type(4)));

__device__ __forceinline__ float sigmoidf_(float x) {
    return 1.0f / (1.0f + __expf(-x));
}
__device__ __forceinline__ float tanh_fast(float x) {
    float ax = fabsf(x);
    float t = 1.0f - 2.0f / (1.0f + __expf(2.0f * ax));
    return copysignf(t, x);
}
__device__ __forceinline__ f32x4 MFMA(f32x4 c, f16x8 a, f16x8 b) {
    return __builtin_amdgcn_mfma_f32_16x16x32_f16(a, b, c, 0, 0, 0);
}

// ---- fused prep: B-hi fragments (blocks 0..15) + rank-1 u/c (block 16) + winner init ----
// B[128][256]: cols 0..63 r (K: x|h), 64..127 z, 128..191 i_n (x only), 192..255 h_n (h only).
// Fragment f = g*4+s; lane l holds B[s*32+(l>>4)*8+j][g*16+(l&15)], j=0..7. fp16 HI only —
// the rank-1 time term carries the magnitude, so no lo-correction plane is needed.
__global__ void k_prep_init(const float* __restrict__ Wih, const float* __restrict__ Whh,
                            const float* __restrict__ Wt, const float* __restrict__ bt,
                            _Float16* __restrict__ bhi, float* __restrict__ u, float* __restrict__ c,
                            int* __restrict__ winner, int num_nodes)
{
    if (blockIdx.x < 16) {
        int f = blockIdx.x * 4 + (threadIdx.x >> 6);   // 0..63
        int l = threadIdx.x & 63;
        int g = f >> 2, s = f & 3;
        int cc = g * 16 + (l & 15);
        int grp = cc >> 6, dd = cc & 63;
        int kbase = s * 32 + (l >> 4) * 8;
        int row = (grp == 0) ? dd : (grp == 1) ? 64 + dd : 128 + dd;

        f16x8 hv;
        for (int j = 0; j < 8; ++j) {
            int k = kbase + j;
            float v;
            if (grp <= 1)      v = (k < 64) ? Wih[row * 64 + k] : Whh[row * 64 + (k - 64)];
            else if (grp == 2) v = (k < 64) ? Wih[row * 64 + k] : 0.0f;
            else               v = (k < 64) ? 0.0f : Whh[row * 64 + (k - 64)];
            hv[j] = (_Float16)v;
        }
        ((f16x8*)bhi)[(size_t)f * 64 + l] = hv;
    } else if (blockIdx.x == 16) {
        // u[row] = Wih[row,:] @ Wt ; c[row] = Wih[row,:] @ bt  (row 0..191)
        int t = threadIdx.x;
        if (t < 192) {
            float su = 0.f, sc = 0.f;
            for (int k = 0; k < 64; ++k) {
                float wv = Wih[t * 64 + k];
                su = fmaf(wv, Wt[k], su);
                sc = fmaf(wv, bt[k], sc);
            }
            u[t] = su;
            c[t] = sc;
        }
    } else {
        int i = (int)(blockIdx.x - 17) * 256 + threadIdx.x;
        if (i < num_nodes) winner[i] = -1;
    }
}

// ---------------- main GRU kernel: rank-1, fused vote+dt, out0 only ----------------
// Phase A: coalesced ids/ts; lanes<16 issue atomicMax vote (fire-and-forget, read
// only by the later k_tail dispatch); lut gather feeds ONLY the epilogue via sdt,
// so its latency hides under staging+MFMA. A = [emb_fp16 | h_fp16].
__global__ __launch_bounds__(256, 4) void k_gru(
    const int* __restrict__ ids,
    const float* __restrict__ emb,
    const float* __restrict__ ts,
    const float* __restrict__ mem,
    const float* __restrict__ lut,
    const float* __restrict__ bih,
    const float* __restrict__ bhh,
    const _Float16* __restrict__ bhi,
    const float* __restrict__ u,
    const float* __restrict__ c,
    int* __restrict__ winner,
    float* __restrict__ out0,
    int n)
{
    __shared__ _Float16 xhh[64][136];   // [event][k]: k<64 emb_fp16, k>=64 h_fp16
    __shared__ float sdt[64];

    const int w    = threadIdx.x >> 6;
    const int l    = threadIdx.x & 63;
    const int col  = l & 15;
    const int rowg = l >> 4;
    const int d    = w * 16 + col;

    const long base = (long)blockIdx.x * 64;
    const bool full = (base + 64 <= (long)n);

    const f32x4* emb4 = (const f32x4*)emb;
    const f32x4* mem4 = (const f32x4*)mem;

    // ---- emb loads: fully independent, issue first ----
    f32x4 xv0, xv1, xv2, xv3;
    {
        const size_t e0 = (size_t)(base + w * 16 + 0 * 4 + rowg) * 16 + col;
        const size_t e1 = (size_t)(base + w * 16 + 1 * 4 + rowg) * 16 + col;
        const size_t e2 = (size_t)(base + w * 16 + 2 * 4 + rowg) * 16 + col;
        const size_t e3 = (size_t)(base + w * 16 + 3 * 4 + rowg) * 16 + col;
        if (full) {
            xv0 = __builtin_nontemporal_load(&emb4[e0]);
            xv1 = __builtin_nontemporal_load(&emb4[e1]);
            xv2 = __builtin_nontemporal_load(&emb4[e2]);
            xv3 = __builtin_nontemporal_load(&emb4[e3]);
        } else {
            f32x4 z = {0.f, 0.f, 0.f, 0.f};
            xv0 = xv1 = xv2 = xv3 = z;
            if (base + w * 16 + 0 * 4 + rowg < n) xv0 = emb4[e0];
            if (base + w * 16 + 1 * 4 + rowg < n) xv1 = emb4[e1];
            if (base + w * 16 + 2 * 4 + rowg < n) xv2 = emb4[e2];
            if (base + w * 16 + 3 * 4 + rowg < n) xv3 = emb4[e3];
        }
    }

    // ---- phase A: coalesced ids/ts; vote (l<16); lut gather -> sdt (epilogue-only) ----
    const int  e16 = w * 16 + col;
    const long evA = base + e16;
    int idA = 0; float dtA = 0.f;
    if (full || evA < n) {
        idA = ids[evA];
        float tsv = ts[evA];
        if (l < 16) atomicMax(&winner[idA], (int)evA);
        dtA = tsv - lut[idA];
    }
    if (l < 16) sdt[e16] = dtA;

    // ---- mem gathers (the one critical-path random hop) ----
    f32x4 hv0, hv1, hv2, hv3;
    {
        int i0 = __shfl(idA, 0 * 4 + rowg), i1 = __shfl(idA, 1 * 4 + rowg);
        int i2 = __shfl(idA, 2 * 4 + rowg), i3 = __shfl(idA, 3 * 4 + rowg);
        if (full) {
            hv0 = mem4[(size_t)i0 * 16 + col];
            hv1 = mem4[(size_t)i1 * 16 + col];
            hv2 = mem4[(size_t)i2 * 16 + col];
            hv3 = mem4[(size_t)i3 * 16 + col];
        } else {
            f32x4 z = {0.f, 0.f, 0.f, 0.f};
            hv0 = hv1 = hv2 = hv3 = z;
            if (base + w * 16 + 0 * 4 + rowg < n) hv0 = mem4[(size_t)i0 * 16 + col];
            if (base + w * 16 + 1 * 4 + rowg < n) hv1 = mem4[(size_t)i1 * 16 + col];
            if (base + w * 16 + 2 * 4 + rowg < n) hv2 = mem4[(size_t)i2 * 16 + col];
            if (base + w * 16 + 3 * 4 + rowg < n) hv3 = mem4[(size_t)i3 * 16 + col];
        }
    }

    // ---- convert + LDS write ----
    #define CONV_WRITE(XV, HV, IT)                                               \
    {                                                                            \
        int r = w * 16 + (IT) * 4 + rowg;                                        \
        f16x4 xh, hh;                                                            \
        xh[0] = (_Float16)(XV).x; xh[1] = (_Float16)(XV).y;                      \
        xh[2] = (_Float16)(XV).z; xh[3] = (_Float16)(XV).w;                      \
        hh[0] = (_Float16)(HV).x; hh[1] = (_Float16)(HV).y;                      \
        hh[2] = (_Float16)(HV).z; hh[3] = (_Float16)(HV).w;                      \
        *(f16x4*)&xhh[r][col * 4]      = xh;                                     \
        *(f16x4*)&xhh[r][64 + col * 4] = hh;                                     \
    }
    CONV_WRITE(xv0, hv0, 0)
    CONV_WRITE(xv1, hv1, 1)
    CONV_WRITE(xv2, hv2, 2)
    CONV_WRITE(xv3, hv3, 3)
    #undef CONV_WRITE

    // ---- B fragments (L2-resident): 12 per wave ----
    const f16x8* H = (const f16x8*)bhi;
    f16x8 BRh0 = H[(size_t)(w * 4 + 0) * 64 + l];
    f16x8 BRh1 = H[(size_t)(w * 4 + 1) * 64 + l];
    f16x8 BRh2 = H[(size_t)(w * 4 + 2) * 64 + l];
    f16x8 BRh3 = H[(size_t)(w * 4 + 3) * 64 + l];
    f16x8 BZh0 = H[(size_t)((4 + w) * 4 + 0) * 64 + l];
    f16x8 BZh1 = H[(size_t)((4 + w) * 4 + 1) * 64 + l];
    f16x8 BZh2 = H[(size_t)((4 + w) * 4 + 2) * 64 + l];
    f16x8 BZh3 = H[(size_t)((4 + w) * 4 + 3) * 64 + l];
    f16x8 BIh0 = H[(size_t)((8 + w) * 4 + 0) * 64 + l];
    f16x8 BIh1 = H[(size_t)((8 + w) * 4 + 1) * 64 + l];
    f16x8 BHh0 = H[(size_t)((12 + w) * 4 + 2) * 64 + l];
    f16x8 BHh1 = H[(size_t)((12 + w) * 4 + 3) * 64 + l];

    // per-lane rank-1 + bias constants
    const float uR = u[d],        uZ = u[64 + d],  uI = u[128 + d];
    const float CR = c[d]        + bih[d]        + bhh[d];
    const float CZ = c[64 + d]   + bih[64 + d]   + bhh[64 + d];
    const float CI = c[128 + d]  + bih[128 + d];
    const float bHN = bhh[128 + d];

    __syncthreads();

    // ---- 4 M-tiles of 16 events each: 12 MFMA per tile ----
    #pragma unroll
    for (int mt = 0; mt < 4; ++mt) {
        const int arow = mt * 16 + col;
        const int k0   = rowg * 8;
        f16x8 Ah0 = *(const f16x8*)&xhh[arow][0 * 32 + k0];
        f16x8 Ah1 = *(const f16x8*)&xhh[arow][1 * 32 + k0];
        f16x8 Ah2 = *(const f16x8*)&xhh[arow][2 * 32 + k0];
        f16x8 Ah3 = *(const f16x8*)&xhh[arow][3 * 32 + k0];

        f32x4 aR = {0,0,0,0}, aZ = {0,0,0,0}, aI = {0,0,0,0}, aH = {0,0,0,0};
        __builtin_amdgcn_s_setprio(1);
        aR = MFMA(aR, Ah0, BRh0); aR = MFMA(aR, Ah1, BRh1);
        aR = MFMA(aR, Ah2, BRh2); aR = MFMA(aR, Ah3, BRh3);
        aZ = MFMA(aZ, Ah0, BZh0); aZ = MFMA(aZ, Ah1, BZh1);
        aZ = MFMA(aZ, Ah2, BZh2); aZ = MFMA(aZ, Ah3, BZh3);
        aI = MFMA(aI, Ah0, BIh0); aI = MFMA(aI, Ah1, BIh1);
        aH = MFMA(aH, Ah2, BHh0); aH = MFMA(aH, Ah3, BHh1);
        __builtin_amdgcn_s_setprio(0);

        #pragma unroll
        for (int r = 0; r < 4; ++r) {
            int  eloc = mt * 16 + rowg * 4 + r;
            long ev   = base + eloc;
            if (full || ev < n) {
                float dt = sdt[eloc];
                float rr = sigmoidf_(aR[r] + fmaf(dt, uR, CR));
                float zz = sigmoidf_(aZ[r] + fmaf(dt, uZ, CZ));
                float nn = tanh_fast(aI[r] + fmaf(dt, uI, CI) + rr * (aH[r] + bHN));
                float hv = (float)xhh[eloc][64 + d];
                float o  = (1.f - zz) * nn + zz * hv;
                out0[(size_t)ev * 64 + d] = o;
            }
        }
    }
}

// ---------------- tail: out1 assembly (gather) + timestamp scatter ----------------
// out1[node] = winner>=0 ? out0[winner[node]] (L2/L3-hot gather) : mem[node];
// out2[node] = winner>=0 ? ts[winner] : lut[node].
// winner stored IN out2; all 16 readers of a node are in the writer's wave -> safe.
__global__ void k_tail(float* out2,
                       const f32x4* __restrict__ mem4,
                       const f32x4* __restrict__ out04,
                       f32x4* __restrict__ out14,
                       const float* __restrict__ ts,
                       const float* __restrict__ lut,
                       int num_nodes)
{
    int idx = blockIdx.x * blockDim.x + threadIdx.x;
    if (idx >= num_nodes * 16) return;
    int nidx = idx >> 4;
    int cc   = idx & 15;
    int wv = reinterpret_cast<const int*>(out2)[nidx];
    f32x4 v;
    if (wv >= 0) {
        v = out04[(size_t)wv * 16 + cc];                       // gather, L2/L3-hot
    } else {
        v = __builtin_nontemporal_load(&mem4[idx]);            // streaming copy
    }
    __builtin_nontemporal_store(v, &out14[idx]);               // coalesced full rows
    if (cc == 0) out2[nidx] = (wv >= 0) ? ts[wv] : lut[nidx];
}

extern "C" void kernel_launch(void* const* d_in, const int* in_sizes, int n_in,
                              void* d_out, int out_size, void* d_ws, size_t ws_size,
                              hipStream_t stream) {
    const int*   ids = (const int*)  d_in[0];
    const float* emb = (const float*)d_in[1];
    const float* ts  = (const float*)d_in[2];
    const float* mem = (const float*)d_in[3];
    const float* lut = (const float*)d_in[4];
    const float* Wt  = (const float*)d_in[5];
    const float* bt  = (const float*)d_in[6];
    const float* Wih = (const float*)d_in[7];
    const float* Whh = (const float*)d_in[8];
    const float* bih = (const float*)d_in[9];
    const float* bhh = (const float*)d_in[10];

    const int N         = in_sizes[0];
    const int NUM_NODES = in_sizes[4];

    float* out0 = (float*)d_out;                    // [N,64]
    float* out1 = out0 + (size_t)N * DD;            // [NUM_NODES,64]
    float* out2 = out1 + (size_t)NUM_NODES * DD;    // [NUM_NODES]
    int*   winner = (int*)out2;                     // winner lives in out2 region

    _Float16* bfragH = (_Float16*)d_ws;                          // 64 KB
    float*    uvec   = (float*)((char*)d_ws + 64 * 1024);        // 192 f
    float*    cvec   = uvec + 192;                               // 192 f

    int initBlocks = (NUM_NODES + 255) / 256;
    k_prep_init<<<17 + initBlocks, 256, 0, stream>>>(Wih, Whh, Wt, bt, bfragH,
                                                     uvec, cvec, winner, NUM_NODES);

    int nchunks = (N + 63) / 64;
    k_gru<<<nchunks, 256, 0, stream>>>(ids, emb, ts, mem, lut, bih, bhh, bfragH,
                                       uvec, cvec, winner, out0, N);

    long vec = (long)NUM_NODES * 16;
    k_tail<<<(int)((vec + 255) / 256), 256, 0, stream>>>(
        out2, (const f32x4*)mem, (const f32x4*)out0, (f32x4*)out1, ts, lut, NUM_NODES);
}

// Round 18
// 201.381 us; speedup vs baseline: 1.4252x; 1.0025x over previous
//
#include <hip/hip_runtime.h>
#include <cstdint>
#include <cstddef>

#define DD 64

typedef float    f32x4  __attribute__((ext_vector_type(4)));
typedef _Float16 f16x8  __attribute__((ext_vector_type(8)));
typedef _Float16 f16x4  __attribute__((ext_vector_type(4)));

__device__ __forceinline__ float sigmoidf_(float x) {
    return 1.0f / (1.0f + __expf(-x));
}
__device__ __forceinline__ float tanh_fast(float x) {
    float ax = fabsf(x);
    float t = 1.0f - 2.0f / (1.0f + __expf(2.0f * ax));
    return copysignf(t, x);
}
__device__ __forceinline__ f32x4 MFMA(f32x4 c, f16x8 a, f16x8 b) {
    return __builtin_amdgcn_mfma_f32_16x16x32_f16(a, b, c, 0, 0, 0);
}

// ---- fused prep: B-hi fragments (blocks 0..15) + rank-1 u/c (block 16) + winner init ----
// B[128][256]: cols 0..63 r (K: x|h), 64..127 z, 128..191 i_n (x only), 192..255 h_n (h only).
// Fragment f = g*4+s; lane l holds B[s*32+(l>>4)*8+j][g*16+(l&15)], j=0..7. fp16 HI only —
// the rank-1 time term carries the magnitude, so no lo-correction plane is needed.
__global__ void k_prep_init(const float* __restrict__ Wih, const float* __restrict__ Whh,
                            const float* __restrict__ Wt, const float* __restrict__ bt,
                            _Float16* __restrict__ bhi, float* __restrict__ u, float* __restrict__ c,
                            int* __restrict__ winner, int num_nodes)
{
    if (blockIdx.x < 16) {
        int f = blockIdx.x * 4 + (threadIdx.x >> 6);   // 0..63
        int l = threadIdx.x & 63;
        int g = f >> 2, s = f & 3;
        int cc = g * 16 + (l & 15);
        int grp = cc >> 6, dd = cc & 63;
        int kbase = s * 32 + (l >> 4) * 8;
        int row = (grp == 0) ? dd : (grp == 1) ? 64 + dd : 128 + dd;

        f16x8 hv;
        for (int j = 0; j < 8; ++j) {
            int k = kbase + j;
            float v;
            if (grp <= 1)      v = (k < 64) ? Wih[row * 64 + k] : Whh[row * 64 + (k - 64)];
            else if (grp == 2) v = (k < 64) ? Wih[row * 64 + k] : 0.0f;
            else               v = (k < 64) ? 0.0f : Whh[row * 64 + (k - 64)];
            hv[j] = (_Float16)v;
        }
        ((f16x8*)bhi)[(size_t)f * 64 + l] = hv;
    } else if (blockIdx.x == 16) {
        // u[row] = Wih[row,:] @ Wt ; c[row] = Wih[row,:] @ bt  (row 0..191)
        int t = threadIdx.x;
        if (t < 192) {
            float su = 0.f, sc = 0.f;
            for (int k = 0; k < 64; ++k) {
                float wv = Wih[t * 64 + k];
                su = fmaf(wv, Wt[k], su);
                sc = fmaf(wv, bt[k], sc);
            }
            u[t] = su;
            c[t] = sc;
        }
    } else {
        int i = (int)(blockIdx.x - 17) * 256 + threadIdx.x;
        if (i < num_nodes) winner[i] = -1;
    }
}

// ---------------- main GRU kernel: rank-1, fused vote+dt, out0 only ----------------
// Phase A: coalesced ids/ts; lanes<16 issue atomicMax vote (fire-and-forget, read
// only by the later k_tail dispatch); lut gather feeds ONLY the epilogue via sdt,
// so its latency hides under staging+MFMA. A = [emb_fp16 | h_fp16].
// launch_bounds(256,5): 5 blocks/CU (20 waves) for more outstanding gathers.
__global__ __launch_bounds__(256, 5) void k_gru(
    const int* __restrict__ ids,
    const float* __restrict__ emb,
    const float* __restrict__ ts,
    const float* __restrict__ mem,
    const float* __restrict__ lut,
    const float* __restrict__ bih,
    const float* __restrict__ bhh,
    const _Float16* __restrict__ bhi,
    const float* __restrict__ u,
    const float* __restrict__ c,
    int* __restrict__ winner,
    float* __restrict__ out0,
    int n)
{
    __shared__ _Float16 xhh[64][136];   // [event][k]: k<64 emb_fp16, k>=64 h_fp16
    __shared__ float sdt[64];

    const int w    = threadIdx.x >> 6;
    const int l    = threadIdx.x & 63;
    const int col  = l & 15;
    const int rowg = l >> 4;
    const int d    = w * 16 + col;

    const long base = (long)blockIdx.x * 64;
    const bool full = (base + 64 <= (long)n);

    const f32x4* emb4 = (const f32x4*)emb;
    const f32x4* mem4 = (const f32x4*)mem;

    // ---- emb loads: fully independent, issue first ----
    f32x4 xv0, xv1, xv2, xv3;
    {
        const size_t e0 = (size_t)(base + w * 16 + 0 * 4 + rowg) * 16 + col;
        const size_t e1 = (size_t)(base + w * 16 + 1 * 4 + rowg) * 16 + col;
        const size_t e2 = (size_t)(base + w * 16 + 2 * 4 + rowg) * 16 + col;
        const size_t e3 = (size_t)(base + w * 16 + 3 * 4 + rowg) * 16 + col;
        if (full) {
            xv0 = __builtin_nontemporal_load(&emb4[e0]);
            xv1 = __builtin_nontemporal_load(&emb4[e1]);
            xv2 = __builtin_nontemporal_load(&emb4[e2]);
            xv3 = __builtin_nontemporal_load(&emb4[e3]);
        } else {
            f32x4 z = {0.f, 0.f, 0.f, 0.f};
            xv0 = xv1 = xv2 = xv3 = z;
            if (base + w * 16 + 0 * 4 + rowg < n) xv0 = emb4[e0];
            if (base + w * 16 + 1 * 4 + rowg < n) xv1 = emb4[e1];
            if (base + w * 16 + 2 * 4 + rowg < n) xv2 = emb4[e2];
            if (base + w * 16 + 3 * 4 + rowg < n) xv3 = emb4[e3];
        }
    }

    // ---- phase A: coalesced ids/ts; vote (l<16); lut gather -> sdt (epilogue-only) ----
    const int  e16 = w * 16 + col;
    const long evA = base + e16;
    int idA = 0; float dtA = 0.f;
    if (full || evA < n) {
        idA = ids[evA];
        float tsv = ts[evA];
        if (l < 16) atomicMax(&winner[idA], (int)evA);
        dtA = tsv - lut[idA];
    }
    if (l < 16) sdt[e16] = dtA;

    // ---- mem gathers (the one critical-path random hop) ----
    f32x4 hv0, hv1, hv2, hv3;
    {
        int i0 = __shfl(idA, 0 * 4 + rowg), i1 = __shfl(idA, 1 * 4 + rowg);
        int i2 = __shfl(idA, 2 * 4 + rowg), i3 = __shfl(idA, 3 * 4 + rowg);
        if (full) {
            hv0 = mem4[(size_t)i0 * 16 + col];
            hv1 = mem4[(size_t)i1 * 16 + col];
            hv2 = mem4[(size_t)i2 * 16 + col];
            hv3 = mem4[(size_t)i3 * 16 + col];
        } else {
            f32x4 z = {0.f, 0.f, 0.f, 0.f};
            hv0 = hv1 = hv2 = hv3 = z;
            if (base + w * 16 + 0 * 4 + rowg < n) hv0 = mem4[(size_t)i0 * 16 + col];
            if (base + w * 16 + 1 * 4 + rowg < n) hv1 = mem4[(size_t)i1 * 16 + col];
            if (base + w * 16 + 2 * 4 + rowg < n) hv2 = mem4[(size_t)i2 * 16 + col];
            if (base + w * 16 + 3 * 4 + rowg < n) hv3 = mem4[(size_t)i3 * 16 + col];
        }
    }

    // ---- convert + LDS write ----
    #define CONV_WRITE(XV, HV, IT)                                               \
    {                                                                            \
        int r = w * 16 + (IT) * 4 + rowg;                                        \
        f16x4 xh, hh;                                                            \
        xh[0] = (_Float16)(XV).x; xh[1] = (_Float16)(XV).y;                      \
        xh[2] = (_Float16)(XV).z; xh[3] = (_Float16)(XV).w;                      \
        hh[0] = (_Float16)(HV).x; hh[1] = (_Float16)(HV).y;                      \
        hh[2] = (_Float16)(HV).z; hh[3] = (_Float16)(HV).w;                      \
        *(f16x4*)&xhh[r][col * 4]      = xh;                                     \
        *(f16x4*)&xhh[r][64 + col * 4] = hh;                                     \
    }
    CONV_WRITE(xv0, hv0, 0)
    CONV_WRITE(xv1, hv1, 1)
    CONV_WRITE(xv2, hv2, 2)
    CONV_WRITE(xv3, hv3, 3)
    #undef CONV_WRITE

    // ---- B fragments (L2-resident): 12 per wave ----
    const f16x8* H = (const f16x8*)bhi;
    f16x8 BRh0 = H[(size_t)(w * 4 + 0) * 64 + l];
    f16x8 BRh1 = H[(size_t)(w * 4 + 1) * 64 + l];
    f16x8 BRh2 = H[(size_t)(w * 4 + 2) * 64 + l];
    f16x8 BRh3 = H[(size_t)(w * 4 + 3) * 64 + l];
    f16x8 BZh0 = H[(size_t)((4 + w) * 4 + 0) * 64 + l];
    f16x8 BZh1 = H[(size_t)((4 + w) * 4 + 1) * 64 + l];
    f16x8 BZh2 = H[(size_t)((4 + w) * 4 + 2) * 64 + l];
    f16x8 BZh3 = H[(size_t)((4 + w) * 4 + 3) * 64 + l];
    f16x8 BIh0 = H[(size_t)((8 + w) * 4 + 0) * 64 + l];
    f16x8 BIh1 = H[(size_t)((8 + w) * 4 + 1) * 64 + l];
    f16x8 BHh0 = H[(size_t)((12 + w) * 4 + 2) * 64 + l];
    f16x8 BHh1 = H[(size_t)((12 + w) * 4 + 3) * 64 + l];

    // per-lane rank-1 + bias constants
    const float uR = u[d],        uZ = u[64 + d],  uI = u[128 + d];
    const float CR = c[d]        + bih[d]        + bhh[d];
    const float CZ = c[64 + d]   + bih[64 + d]   + bhh[64 + d];
    const float CI = c[128 + d]  + bih[128 + d];
    const float bHN = bhh[128 + d];

    __syncthreads();

    // ---- 4 M-tiles of 16 events each: 12 MFMA per tile ----
    #pragma unroll
    for (int mt = 0; mt < 4; ++mt) {
        const int arow = mt * 16 + col;
        const int k0   = rowg * 8;
        f16x8 Ah0 = *(const f16x8*)&xhh[arow][0 * 32 + k0];
        f16x8 Ah1 = *(const f16x8*)&xhh[arow][1 * 32 + k0];
        f16x8 Ah2 = *(const f16x8*)&xhh[arow][2 * 32 + k0];
        f16x8 Ah3 = *(const f16x8*)&xhh[arow][3 * 32 + k0];

        f32x4 aR = {0,0,0,0}, aZ = {0,0,0,0}, aI = {0,0,0,0}, aH = {0,0,0,0};
        __builtin_amdgcn_s_setprio(1);
        aR = MFMA(aR, Ah0, BRh0); aR = MFMA(aR, Ah1, BRh1);
        aR = MFMA(aR, Ah2, BRh2); aR = MFMA(aR, Ah3, BRh3);
        aZ = MFMA(aZ, Ah0, BZh0); aZ = MFMA(aZ, Ah1, BZh1);
        aZ = MFMA(aZ, Ah2, BZh2); aZ = MFMA(aZ, Ah3, BZh3);
        aI = MFMA(aI, Ah0, BIh0); aI = MFMA(aI, Ah1, BIh1);
        aH = MFMA(aH, Ah2, BHh0); aH = MFMA(aH, Ah3, BHh1);
        __builtin_amdgcn_s_setprio(0);

        #pragma unroll
        for (int r = 0; r < 4; ++r) {
            int  eloc = mt * 16 + rowg * 4 + r;
            long ev   = base + eloc;
            if (full || ev < n) {
                float dt = sdt[eloc];
                float rr = sigmoidf_(aR[r] + fmaf(dt, uR, CR));
                float zz = sigmoidf_(aZ[r] + fmaf(dt, uZ, CZ));
                float nn = tanh_fast(aI[r] + fmaf(dt, uI, CI) + rr * (aH[r] + bHN));
                float hv = (float)xhh[eloc][64 + d];
                float o  = (1.f - zz) * nn + zz * hv;
                out0[(size_t)ev * 64 + d] = o;
            }
        }
    }
}

// ---------------- tail: out1 assembly (gather) + timestamp scatter ----------------
// out1[node] = winner>=0 ? out0[winner[node]] (L2/L3-hot gather) : mem[node];
// out2[node] = winner>=0 ? ts[winner] : lut[node].
// winner stored IN out2; all 16 readers of a node are in the writer's wave -> safe.
__global__ void k_tail(float* out2,
                       const f32x4* __restrict__ mem4,
                       const f32x4* __restrict__ out04,
                       f32x4* __restrict__ out14,
                       const float* __restrict__ ts,
                       const float* __restrict__ lut,
                       int num_nodes)
{
    int idx = blockIdx.x * blockDim.x + threadIdx.x;
    if (idx >= num_nodes * 16) return;
    int nidx = idx >> 4;
    int cc   = idx & 15;
    int wv = reinterpret_cast<const int*>(out2)[nidx];
    f32x4 v;
    if (wv >= 0) {
        v = out04[(size_t)wv * 16 + cc];                       // gather, L2/L3-hot
    } else {
        v = __builtin_nontemporal_load(&mem4[idx]);            // streaming copy
    }
    __builtin_nontemporal_store(v, &out14[idx]);               // coalesced full rows
    if (cc == 0) out2[nidx] = (wv >= 0) ? ts[wv] : lut[nidx];
}

extern "C" void kernel_launch(void* const* d_in, const int* in_sizes, int n_in,
                              void* d_out, int out_size, void* d_ws, size_t ws_size,
                              hipStream_t stream) {
    const int*   ids = (const int*)  d_in[0];
    const float* emb = (const float*)d_in[1];
    const float* ts  = (const float*)d_in[2];
    const float* mem = (const float*)d_in[3];
    const float* lut = (const float*)d_in[4];
    const float* Wt  = (const float*)d_in[5];
    const float* bt  = (const float*)d_in[6];
    const float* Wih = (const float*)d_in[7];
    const float* Whh = (const float*)d_in[8];
    const float* bih = (const float*)d_in[9];
    const float* bhh = (const float*)d_in[10];

    const int N         = in_sizes[0];
    const int NUM_NODES = in_sizes[4];

    float* out0 = (float*)d_out;                    // [N,64]
    float* out1 = out0 + (size_t)N * DD;            // [NUM_NODES,64]
    float* out2 = out1 + (size_t)NUM_NODES * DD;    // [NUM_NODES]
    int*   winner = (int*)out2;                     // winner lives in out2 region

    _Float16* bfragH = (_Float16*)d_ws;                          // 64 KB
    float*    uvec   = (float*)((char*)d_ws + 64 * 1024);        // 192 f
    float*    cvec   = uvec + 192;                               // 192 f

    int initBlocks = (NUM_NODES + 255) / 256;
    k_prep_init<<<17 + initBlocks, 256, 0, stream>>>(Wih, Whh, Wt, bt, bfragH,
                                                     uvec, cvec, winner, NUM_NODES);

    int nchunks = (N + 63) / 64;
    k_gru<<<nchunks, 256, 0, stream>>>(ids, emb, ts, mem, lut, bih, bhh, bfragH,
                                       uvec, cvec, winner, out0, N);

    long vec = (long)NUM_NODES * 16;
    k_tail<<<(int)((vec + 255) / 256), 256, 0, stream>>>(
        out2, (const f32x4*)mem, (const f32x4*)out0, (f32x4*)out1, ts, lut, NUM_NODES);
}